// Round 1
// baseline (51.530 us; speedup 1.0000x reference)
//
#include <hip/hip_runtime.h>

// Shapes (fixed by setup_inputs): B=4, D=20, H=W=128, HW=16384, K=B*HW=65536.
#define HW 16384

__global__ __launch_bounds__(256) void chamfer_main(
    const float* __restrict__ pred,   // [B, 60, HW]  channel c*20+d
    const float* __restrict__ gt,     // [B, 60, HW]  channel d*3+c
    const float* __restrict__ cmask,  // [B, 20, HW]
    const float* __restrict__ vmask,  // [B, HW]
    const float* __restrict__ pnum,   // [B, HW]
    const float* __restrict__ gnum,   // [B, HW]
    float* __restrict__ ws)
{
    const int k  = blockIdx.x * blockDim.x + threadIdx.x;
    const int b  = k >> 14;          // k / HW
    const int hw = k & (HW - 1);     // k % HW
    const size_t pbase = (size_t)b * 60 * HW + hw;
    const size_t cbase = (size_t)b * 20 * HW + hw;

    // Load gt (dst) points: dst[j][c] = gt[b, j*3+c, hw]
    float dst[60];
    #pragma unroll
    for (int t = 0; t < 60; ++t) dst[t] = gt[pbase + (size_t)t * HW];

    // chamfer mask -> bitmask (values are exactly 0.0 / 1.0)
    unsigned cmbits = 0u;
    #pragma unroll
    for (int j = 0; j < 20; ++j) {
        float c = cmask[cbase + (size_t)j * HW];
        if (c > 0.f) cmbits |= (1u << j);
    }

    const float INF = __int_as_float(0x7f800000);
    float d2s[20];
    #pragma unroll
    for (int j = 0; j < 20; ++j) d2s[j] = INF;

    float srcA = 0.f;      // sum_i (m1_i if any mask else m0_i)
    float locmax = 0.f;    // local max of dist
    for (int i = 0; i < 20; ++i) {
        float sx = pred[pbase + (size_t)(i)      * HW];
        float sy = pred[pbase + (size_t)(20 + i) * HW];
        float sz = pred[pbase + (size_t)(40 + i) * HW];
        float m1 = INF, m0 = INF;
        #pragma unroll
        for (int j = 0; j < 20; ++j) {
            float d = fabsf(sx - dst[3*j]) + fabsf(sy - dst[3*j+1]) + fabsf(sz - dst[3*j+2]);
            locmax  = fmaxf(locmax, d);
            d2s[j]  = fminf(d2s[j], d);
            if ((cmbits >> j) & 1u) m1 = fminf(m1, d);
            else                    m0 = fminf(m0, d);
        }
        srcA += (cmbits != 0u) ? m1 : m0;
    }

    const float vw = vmask[k];
    srcA *= vw;
    float srcC = (cmbits == 0u) ? 20.f * vw : 0.f;   // rows needing +max_d

    float dstnum = 0.f;
    #pragma unroll
    for (int j = 0; j < 20; ++j)
        if ((cmbits >> j) & 1u) dstnum += d2s[j];
    dstnum *= vw;
    float dstden = vw * (float)__popc(cmbits);
    if (vw <= 0.f) locmax = 0.f;   // max only over vw>0 voxels

    // smooth L1 (beta=1) num-loss part
    float diff = pnum[k] - gnum[k];
    float ad = fabsf(diff);
    float sl1 = (ad < 1.f) ? 0.5f * diff * diff : (ad - 0.5f);
    float numnum = sl1 * vw;
    float wsum = vw;

    // block reduction: 6 sums + 1 max
    float vals[7] = {srcA, srcC, dstnum, dstden, numnum, wsum, locmax};
    #pragma unroll
    for (int off = 32; off > 0; off >>= 1) {
        #pragma unroll
        for (int v = 0; v < 6; ++v) vals[v] += __shfl_down(vals[v], off);
        vals[6] = fmaxf(vals[6], __shfl_down(vals[6], off));
    }
    __shared__ float red[4][8];
    const int lane = threadIdx.x & 63;
    const int wv   = threadIdx.x >> 6;
    if (lane == 0) {
        #pragma unroll
        for (int v = 0; v < 7; ++v) red[wv][v] = vals[v];
    }
    __syncthreads();
    if (threadIdx.x == 0) {
        float acc[7];
        #pragma unroll
        for (int v = 0; v < 7; ++v) acc[v] = red[0][v];
        for (int w = 1; w < 4; ++w) {
            #pragma unroll
            for (int v = 0; v < 6; ++v) acc[v] += red[w][v];
            acc[6] = fmaxf(acc[6], red[w][6]);
        }
        #pragma unroll
        for (int v = 0; v < 6; ++v) atomicAdd(&ws[v], acc[v]);
        atomicMax((int*)&ws[6], __float_as_int(acc[6]));   // dist >= 0, int-max == float-max
    }
}

__global__ void chamfer_fin(const float* __restrict__ ws, float* __restrict__ out)
{
    const float maxd   = ws[6];
    const float wsum   = ws[5];
    const float loss_s = (ws[0] + ws[1] * maxd) / (wsum * 20.f);
    const float loss_d = ws[2] / ws[3];
    const float numl   = ws[4] / ws[5];
    out[0] = loss_s + loss_d + 0.1f * numl;
}

extern "C" void kernel_launch(void* const* d_in, const int* in_sizes, int n_in,
                              void* d_out, int out_size, void* d_ws, size_t ws_size,
                              hipStream_t stream)
{
    const float* pred  = (const float*)d_in[0];
    const float* gt    = (const float*)d_in[1];
    const float* cmask = (const float*)d_in[2];
    const float* vmask = (const float*)d_in[3];
    const float* pnum  = (const float*)d_in[4];
    const float* gnum  = (const float*)d_in[5];
    float* out = (float*)d_out;
    float* ws  = (float*)d_ws;

    const int nvox = in_sizes[3];           // B*H*W = 65536
    hipMemsetAsync(ws, 0, 8 * sizeof(float), stream);
    chamfer_main<<<nvox / 256, 256, 0, stream>>>(pred, gt, cmask, vmask, pnum, gnum, ws);
    chamfer_fin<<<1, 1, 0, stream>>>(ws, out);
}